// Round 1
// baseline (187.158 us; speedup 1.0000x reference)
//
#include <hip/hip_runtime.h>

#define BB 32
#define NN 1024
#define EE 16384
#define DSS 8
#define HH 32

// prio[i*N+j] = max over all writes to (i,j) of (pass*E + e); -1 if untouched.
// pass 0 = (src,dst) assignment, pass 1 = (dst,src) assignment.
// max-priority == last sequential NumPy write -> deterministic last-write-wins.

// One thread per (b,e): compute score AND init 2 prio ints (2*524288 = N*N).
__global__ void prep_kernel(const float* __restrict__ xyz,
                            const int* __restrict__ edge_index,
                            const int* __restrict__ edge_type,
                            const float* __restrict__ rest_len,
                            const float* __restrict__ type_emb,
                            const float* __restrict__ w1,
                            const float* __restrict__ b1,
                            const float* __restrict__ w2,
                            const float* __restrict__ b2,
                            float* __restrict__ score,
                            int* __restrict__ prio) {
    int idx = blockIdx.x * 256 + threadIdx.x;      // b*E + e, in [0, B*E)
    ((int2*)prio)[idx] = make_int2(-1, -1);        // fused prio init, 8 B/thread
    int e = idx & (EE - 1);
    int b = idx >> 14;                             // E = 2^14
    int src = edge_index[e];
    int dst = edge_index[EE + e];
    const float* ps = xyz + ((size_t)b * NN + src) * 3;
    const float* pd = xyz + ((size_t)b * NN + dst) * 3;
    float dx = pd[0] - ps[0];
    float dy = pd[1] - ps[1];
    float dz = pd[2] - ps[2];
    float dist = sqrtf(dx * dx + dy * dy + dz * dz + 1e-12f);
    float rest = rest_len[e];
    int ty = edge_type[e];
    float f0 = dist, f1 = rest, f2 = dist - rest;

    float emb[DSS];
#pragma unroll
    for (int k = 0; k < DSS; ++k) emb[k] = type_emb[ty * DSS + k];

    float acc = b2[0];
#pragma unroll
    for (int j = 0; j < HH; ++j) {
        float h = b1[j];
        h = fmaf(f0, w1[0 * HH + j], h);
        h = fmaf(f1, w1[1 * HH + j], h);
        h = fmaf(f2, w1[2 * HH + j], h);
#pragma unroll
        for (int k = 0; k < DSS; ++k)
            h = fmaf(emb[k], w1[(3 + k) * HH + j], h);
        h = fmaxf(h, 0.0f);
        acc = fmaf(w2[j], h, acc);
    }
    score[idx] = acc;
}

__global__ void build_prio(const int* __restrict__ edge_index, int* __restrict__ prio) {
    int t = blockIdx.x * blockDim.x + threadIdx.x;   // t in [0, 2E); t == pass*E + e
    int pass = t >= EE;
    int e = t - pass * EE;
    int src = edge_index[e];
    int dst = edge_index[EE + e];
    int i = pass ? dst : src;
    int j = pass ? src : dst;
    atomicMax(&prio[i * NN + j], t);
}

// Block i: owns row i for ALL 32 batches (prio row read once, compaction once).
// Default float4 stream is issued BEFORE the compaction's load-use so the
// write pipe starts immediately; prio-load latency hides under it.
// Scalar fixups after __syncthreads hit lines already dirty in L2.
__global__ void fill_kernel(const int* __restrict__ prio,
                            const float* __restrict__ score,
                            const float* __restrict__ default_bias,
                            float* __restrict__ out) {
    __shared__ int s_col[1024];   // worst case: every column scattered
    __shared__ int s_e[1024];
    __shared__ int s_cnt;
    int i = blockIdx.x;
    int tid = threadIdx.x;

    if (tid == 0) s_cnt = 0;
    __syncthreads();

    int4 p = *(const int4*)(prio + (size_t)i * NN + tid * 4);   // issued early

    float defv = default_bias[0];
    float4 dv = make_float4(defv, defv, defv, defv);
    float* base = out + (size_t)i * NN + tid * 4;
#pragma unroll
    for (int b = 0; b < BB; ++b)
        *(float4*)(base + (size_t)b * NN * NN) = dv;            // independent of p

    if (p.x >= 0) { int s = atomicAdd(&s_cnt, 1); s_col[s] = tid * 4 + 0; s_e[s] = p.x & (EE - 1); }
    if (p.y >= 0) { int s = atomicAdd(&s_cnt, 1); s_col[s] = tid * 4 + 1; s_e[s] = p.y & (EE - 1); }
    if (p.z >= 0) { int s = atomicAdd(&s_cnt, 1); s_col[s] = tid * 4 + 2; s_e[s] = p.z & (EE - 1); }
    if (p.w >= 0) { int s = atomicAdd(&s_cnt, 1); s_col[s] = tid * 4 + 3; s_e[s] = p.w & (EE - 1); }

    __syncthreads();              // orders default stores before fixup overwrites (block-local)

    int total = s_cnt << 5;       // cnt * 32 batches
    for (int w = tid; w < total; w += 256) {
        int c = w >> 5;
        int b = w & 31;
        out[(size_t)b * NN * NN + (size_t)i * NN + s_col[c]] = score[(size_t)b * EE + s_e[c]];
    }
}

extern "C" void kernel_launch(void* const* d_in, const int* in_sizes, int n_in,
                              void* d_out, int out_size, void* d_ws, size_t ws_size,
                              hipStream_t stream) {
    const float* xyz       = (const float*)d_in[0];
    const int*   edge_idx  = (const int*)  d_in[1];
    const int*   edge_type = (const int*)  d_in[2];
    const float* rest_len  = (const float*)d_in[3];
    const float* type_emb  = (const float*)d_in[4];
    const float* w1        = (const float*)d_in[5];
    const float* b1        = (const float*)d_in[6];
    const float* w2        = (const float*)d_in[7];
    const float* b2        = (const float*)d_in[8];
    const float* def_bias  = (const float*)d_in[9];
    float* out = (float*)d_out;

    int*   prio  = (int*)d_ws;                                   // N*N ints  = 4 MB
    float* score = (float*)((char*)d_ws + (size_t)NN * NN * 4);  // B*E floats = 2 MB

    prep_kernel<<<2048, 256, 0, stream>>>(xyz, edge_idx, edge_type, rest_len,
                                          type_emb, w1, b1, w2, b2, score, prio);
    build_prio<<<(2 * EE) / 256, 256, 0, stream>>>(edge_idx, prio);
    fill_kernel<<<NN, 256, 0, stream>>>(prio, score, def_bias, out);
}

// Round 2
// 179.657 us; speedup vs baseline: 1.0418x; 1.0418x over previous
//
#include <hip/hip_runtime.h>

#define BB 32
#define NN 1024
#define EE 16384
#define DSS 8
#define HH 32

// prio[i*N+j] = max over all writes to (i,j) of (pass*E + e); -1 if untouched.
// pass 0 = (src,dst), pass 1 = (dst,src). max-priority == last sequential
// NumPy write -> deterministic last-write-wins.
// prio is pre-initialized to -1 by hipMemsetAsync(0xFF) BEFORE this kernel,
// so the scatter atomics can run here (stream order guarantees init done).

// One thread per (b,e): default-fill 16 float4 of out (write-BW-bound stream),
// compute score, and (for idx < 2E) do the prio atomicMax — compute and
// atomics hide under the 128 MiB store stream.
__global__ void prep_kernel(const float* __restrict__ xyz,
                            const int* __restrict__ edge_index,
                            const int* __restrict__ edge_type,
                            const float* __restrict__ rest_len,
                            const float* __restrict__ type_emb,
                            const float* __restrict__ w1,
                            const float* __restrict__ b1,
                            const float* __restrict__ w2,
                            const float* __restrict__ b2,
                            const float* __restrict__ default_bias,
                            float* __restrict__ score,
                            int* __restrict__ prio,
                            float* __restrict__ out) {
    int idx = blockIdx.x * 256 + threadIdx.x;      // b*E + e, in [0, B*E)

    // ---- default-fill stream: 128 MiB total, 16 float4/thread, coalesced ----
    float defv = default_bias[0];
    float4 dv = make_float4(defv, defv, defv, defv);
    float4* o4 = (float4*)out;                     // 8,388,608 float4 entries
#pragma unroll
    for (int k = 0; k < 16; ++k)
        o4[(size_t)k * 524288 + idx] = dv;         // wave: 1 KB contiguous/store

    // ---- per-(b,e) score ----
    int e = idx & (EE - 1);
    int b = idx >> 14;                             // E = 2^14
    int src = edge_index[e];
    int dst = edge_index[EE + e];
    const float* ps = xyz + ((size_t)b * NN + src) * 3;
    const float* pd = xyz + ((size_t)b * NN + dst) * 3;
    float dx = pd[0] - ps[0];
    float dy = pd[1] - ps[1];
    float dz = pd[2] - ps[2];
    float dist = sqrtf(dx * dx + dy * dy + dz * dz + 1e-12f);
    float rest = rest_len[e];
    int ty = edge_type[e];
    float f0 = dist, f1 = rest, f2 = dist - rest;

    float emb[DSS];
#pragma unroll
    for (int k = 0; k < DSS; ++k) emb[k] = type_emb[ty * DSS + k];

    float acc = b2[0];
#pragma unroll
    for (int j = 0; j < HH; ++j) {
        float h = b1[j];
        h = fmaf(f0, w1[0 * HH + j], h);
        h = fmaf(f1, w1[1 * HH + j], h);
        h = fmaf(f2, w1[2 * HH + j], h);
#pragma unroll
        for (int k = 0; k < DSS; ++k)
            h = fmaf(emb[k], w1[(3 + k) * HH + j], h);
        h = fmaxf(h, 0.0f);
        acc = fmaf(w2[j], h, acc);
    }
    score[idx] = acc;

    // ---- fused build_prio: t = idx in [0, 2E); reuses src/dst loads ----
    if (idx < 2 * EE) {
        int pass = idx >= EE;                      // e == idx & (EE-1) holds
        int i = pass ? dst : src;
        int j = pass ? src : dst;
        atomicMax(&prio[i * NN + j], idx);
    }
}

// Block i: fixups only. Read prio row, compact scattered columns into LDS,
// scatter score into the (already default-filled) output for all 32 batches.
__global__ void fixup_kernel(const int* __restrict__ prio,
                             const float* __restrict__ score,
                             float* __restrict__ out) {
    __shared__ int s_col[1024];   // worst case: every column of the row touched
    __shared__ int s_e[1024];
    __shared__ int s_cnt;
    int i = blockIdx.x;
    int tid = threadIdx.x;

    if (tid == 0) s_cnt = 0;
    __syncthreads();

    int4 p = *(const int4*)(prio + (size_t)i * NN + tid * 4);
    if (p.x >= 0) { int s = atomicAdd(&s_cnt, 1); s_col[s] = tid * 4 + 0; s_e[s] = p.x & (EE - 1); }
    if (p.y >= 0) { int s = atomicAdd(&s_cnt, 1); s_col[s] = tid * 4 + 1; s_e[s] = p.y & (EE - 1); }
    if (p.z >= 0) { int s = atomicAdd(&s_cnt, 1); s_col[s] = tid * 4 + 2; s_e[s] = p.z & (EE - 1); }
    if (p.w >= 0) { int s = atomicAdd(&s_cnt, 1); s_col[s] = tid * 4 + 3; s_e[s] = p.w & (EE - 1); }

    __syncthreads();

    int total = s_cnt << 5;       // cnt * 32 batches
    for (int w = tid; w < total; w += 256) {
        int c = w >> 5;
        int b = w & 31;
        out[(size_t)b * NN * NN + (size_t)i * NN + s_col[c]] = score[(size_t)b * EE + s_e[c]];
    }
}

extern "C" void kernel_launch(void* const* d_in, const int* in_sizes, int n_in,
                              void* d_out, int out_size, void* d_ws, size_t ws_size,
                              hipStream_t stream) {
    const float* xyz       = (const float*)d_in[0];
    const int*   edge_idx  = (const int*)  d_in[1];
    const int*   edge_type = (const int*)  d_in[2];
    const float* rest_len  = (const float*)d_in[3];
    const float* type_emb  = (const float*)d_in[4];
    const float* w1        = (const float*)d_in[5];
    const float* b1        = (const float*)d_in[6];
    const float* w2        = (const float*)d_in[7];
    const float* b2        = (const float*)d_in[8];
    const float* def_bias  = (const float*)d_in[9];
    float* out = (float*)d_out;

    int*   prio  = (int*)d_ws;                                   // N*N ints  = 4 MB
    float* score = (float*)((char*)d_ws + (size_t)NN * NN * 4);  // B*E floats = 2 MB

    hipMemsetAsync(prio, 0xFF, (size_t)NN * NN * 4, stream);     // prio = -1 (graph-capturable)
    prep_kernel<<<2048, 256, 0, stream>>>(xyz, edge_idx, edge_type, rest_len,
                                          type_emb, w1, b1, w2, b2, def_bias,
                                          score, prio, out);
    fixup_kernel<<<NN, 256, 0, stream>>>(prio, score, out);
}